// Round 8
// baseline (34.573 us; speedup 1.0000x reference)
//
#include <hip/hip_runtime.h>
#include <math.h>

constexpr int NB = 4;
constexpr int NN = 512;
constexpr int ND = 32;
constexpr int NPE = 16;
constexpr float INV_SQRT_D = 0.17677669529663687f; // 1/sqrt(32)
constexpr float KSHARP = 10.0f;
constexpr float LN2 = 0.69314718055994531f;

// Single fused kernel. TI=4 rows/block, 512 threads, 512 blocks (2 blocks/CU).
// out[i,d] = A2 + b2*(A4 + hi*A3 - L2i*A5) + hi*(S1 - b2*L2i*S3)
//   c2=W*e*sig, c3=W*(1-sig), c4=W*sig, e=Ej-Ei, b2=beta_d*ln2
// R7: latency-hiding pass — entry prefetch of phase-B globals, pre-barrier
// phase-E h prefetch, two-level final reduce.
__global__ __launch_bounds__(512, 4) void fpg_kernel(
    const float* __restrict__ h,
    const float* __restrict__ pe,
    const float* __restrict__ E,
    const float* __restrict__ A,
    const float* __restrict__ Wk,
    const float* __restrict__ bk,
    const float* __restrict__ Wq,
    const float* __restrict__ bq,
    const float* __restrict__ beta,
    float* __restrict__ out)
{
    const int blk = blockIdx.x;          // 512 blocks = 4 batches x 128 tiles
    const int b   = blk >> 7;
    const int i0  = (blk & 127) << 2;    // 4 rows per block
    const int t   = threadIdx.x;
    const int r    = t >> 7;             // row handled in phase B
    const int jj   = t & 127;
    const int i    = i0 + r;
    const int lane = t & 63;
    const int wh   = (t >> 6) & 1;

    __shared__ __align__(16) float sK[4][ND];
    __shared__ float sKWq[4][20];                       // 17 used
    __shared__ __align__(16) float sCoefP[3][2][NN][2]; // [coef][rowpair][j][ri] 24 KB
    __shared__ float sPart[4][2][4];                    // [row][wave-half][max,s0,s1,s2]
    __shared__ float sS1[4], sS3[4];
    __shared__ __align__(16) float4 sRed4[32][33];      // [g][row*8+dq], pad 33
    __shared__ float sFin[4][4][ND];                    // [quarter][row][d] 2 KB

    const float* h_b  = h  + (size_t)b * NN * ND;
    const float* pe_b = pe + (size_t)b * NN * NPE;

    // ==== ENTRY PREFETCH: all phase-B globals (consumed after 2 barriers) ====
    float4 pjv[4][4];
    float av[4], ejv[4];
    #pragma unroll
    for (int k = 0; k < 4; ++k) {
        const int j = jj + (k << 7);
        const float4* pj = (const float4*)(pe_b + (size_t)j * NPE);
        pjv[k][0] = pj[0]; pjv[k][1] = pj[1]; pjv[k][2] = pj[2]; pjv[k][3] = pj[3];
        av[k]  = A[(size_t)i * NN + j];
        ejv[k] = E[j];
    }
    const float Ei = E[i];

    // ---- Phase A: K rows = pe_i @ Wk + bk ----
    if (t < 128) {
        const int rr = t >> 5, d = t & 31;
        const float* pe_i = pe_b + (size_t)(i0 + rr) * NPE;
        float k = bk[d];
        #pragma unroll
        for (int p = 0; p < NPE; ++p) k = fmaf(pe_i[p], Wk[p * ND + d], k);
        sK[rr][d] = k;
    }
    __syncthreads();

    // ---- Phase A2: KWq[r][p] = K_r . Wq[p,:]; [16] = K_r . bq ----
    if (t < 128) {
        const int rr = t >> 5, q = t & 31;
        if (q < 17) {
            const float* wrow = (q < 16) ? (Wq + q * ND) : bq;
            float acc = 0.f;
            #pragma unroll
            for (int d = 0; d < ND; ++d) acc = fmaf(sK[rr][d], wrow[d], acc);
            sKWq[rr][q] = acc;
        }
    }
    __syncthreads();

    // ---- Phase B: scores from prefetched regs ----
    float kq[17];
    #pragma unroll
    for (int p = 0; p < 17; ++p) kq[p] = sKWq[r][p];

    float sc[4], ed[4], sg[4];
    #pragma unroll
    for (int k = 0; k < 4; ++k) {
        const float4 p0 = pjv[k][0], p1 = pjv[k][1], p2 = pjv[k][2], p3 = pjv[k][3];
        float dot = kq[16];
        dot = fmaf(p0.x, kq[0],  dot); dot = fmaf(p0.y, kq[1],  dot);
        dot = fmaf(p0.z, kq[2],  dot); dot = fmaf(p0.w, kq[3],  dot);
        dot = fmaf(p1.x, kq[4],  dot); dot = fmaf(p1.y, kq[5],  dot);
        dot = fmaf(p1.z, kq[6],  dot); dot = fmaf(p1.w, kq[7],  dot);
        dot = fmaf(p2.x, kq[8],  dot); dot = fmaf(p2.y, kq[9],  dot);
        dot = fmaf(p2.z, kq[10], dot); dot = fmaf(p2.w, kq[11], dot);
        dot = fmaf(p3.x, kq[12], dot); dot = fmaf(p3.y, kq[13], dot);
        dot = fmaf(p3.z, kq[14], dot); dot = fmaf(p3.w, kq[15], dot);
        sc[k] = av[k] * dot * INV_SQRT_D;
        const float e = ejv[k] - Ei;
        ed[k] = e;
        sg[k] = 1.0f / (1.0f + __expf(-KSHARP * e));
    }

    // ---- Phase C: per-row softmax stats over this row's 2 waves ----
    float m = fmaxf(fmaxf(sc[0], sc[1]), fmaxf(sc[2], sc[3]));
    #pragma unroll
    for (int off = 32; off >= 1; off >>= 1) m = fmaxf(m, __shfl_xor(m, off));
    if (lane == 0) sPart[r][wh][0] = m;
    __syncthreads();
    const float M = fmaxf(sPart[r][0][0], sPart[r][1][0]);

    float eh[4];
    float s0 = 0.f, s1 = 0.f, s2 = 0.f;
    #pragma unroll
    for (int k = 0; k < 4; ++k) {
        eh[k] = __expf(sc[k] - M);
        const float om = 1.0f - sg[k];
        s0 += eh[k];
        s1 += eh[k] * ed[k] * om;
        s2 += eh[k] * om;
    }
    #pragma unroll
    for (int off = 32; off >= 1; off >>= 1) {
        s0 += __shfl_xor(s0, off);
        s1 += __shfl_xor(s1, off);
        s2 += __shfl_xor(s2, off);
    }
    if (lane == 0) { sPart[r][wh][1] = s0; sPart[r][wh][2] = s1; sPart[r][wh][3] = s2; }
    __syncthreads();
    const float S   = sPart[r][0][1] + sPart[r][1][1];
    const float inv = 1.0f / S;
    if ((t & 127) == 0) {
        sS1[r] = (sPart[r][0][2] + sPart[r][1][2]) * inv;   // sum W*e*(1-sig)
        sS3[r] = (sPart[r][0][3] + sPart[r][1][3]) * inv;   // sum W*(1-sig)
    }

    // ==== phase-E identity + FIRST-HALF h prefetch (before phase-D barrier) ====
    const int rh = t >> 8;             // row-pair
    const int dq = t & 7;
    const int d0 = dq << 2;
    const int g  = (t >> 3) & 31;      // 32 j-groups
    float4 hva[8];
    #pragma unroll
    for (int q = 0; q < 8; ++q)
        hva[q] = *(const float4*)(h_b + (size_t)((q << 5) + g) * ND + d0);

    // ---- Phase D: publish c2,c3,c4 ----
    const int rp = r >> 1, ri = r & 1;
    #pragma unroll
    for (int k = 0; k < 4; ++k) {
        const int j = jj + (k << 7);
        const float w  = eh[k] * inv;
        const float c4 = w * sg[k];
        const float c3 = w - c4;
        const float c2 = w * ed[k] * sg[k];
        sCoefP[0][rp][j][ri] = c2;
        sCoefP[1][rp][j][ri] = c3;
        sCoefP[2][rp][j][ri] = c4;
    }
    __syncthreads();

    // ==== SECOND-HALF h prefetch (covered by first-half compute) ====
    float4 hvb[8];
    #pragma unroll
    for (int q = 0; q < 8; ++q)
        hvb[q] = *(const float4*)(h_b + (size_t)(((q + 8) << 5) + g) * ND + d0);

    // ---- Phase E: 16 j per thread, C-reads amortized over d-quad ----
    float acc[2][4][4] = {};           // [row-in-pair][A2,A3,A4,A5][comp]
    #pragma unroll
    for (int q = 0; q < 16; ++q) {
        const int j = (q << 5) + g;
        const float2 C2 = *(const float2*)&sCoefP[0][rh][j][0];
        const float2 C3 = *(const float2*)&sCoefP[1][rh][j][0];
        const float2 C4 = *(const float2*)&sCoefP[2][rh][j][0];
        const float4 hv4 = (q < 8) ? hva[q & 7] : hvb[q & 7];
        const float hvv[4] = {hv4.x, hv4.y, hv4.z, hv4.w};
        const float cc2[2] = {C2.x, C2.y};
        const float cc3[2] = {C3.x, C3.y};
        const float cc4[2] = {C4.x, C4.y};
        #pragma unroll
        for (int c = 0; c < 4; ++c) {
            const float hvc = hvv[c];
            const float l2  = __log2f(hvc + 1e-8f);
            const float hl  = hvc * l2;
            #pragma unroll
            for (int r2 = 0; r2 < 2; ++r2) {
                acc[r2][0][c] = fmaf(cc2[r2], hvc, acc[r2][0][c]);
                acc[r2][1][c] = fmaf(cc3[r2], l2,  acc[r2][1][c]);
                acc[r2][2][c] = fmaf(cc4[r2], hl,  acc[r2][2][c]);
                acc[r2][3][c] = fmaf(cc4[r2], hvc, acc[r2][3][c]);
            }
        }
    }
    const float4 bet = *(const float4*)(beta + d0);
    const float b2v[4] = {bet.x * LN2, bet.y * LN2, bet.z * LN2, bet.w * LN2};
    #pragma unroll
    for (int r2 = 0; r2 < 2; ++r2) {
        const int row = (rh << 1) + r2;
        const float4 hi4 = *(const float4*)(h_b + (size_t)(i0 + row) * ND + d0);
        const float hiv[4] = {hi4.x, hi4.y, hi4.z, hi4.w};
        float pv[4];
        #pragma unroll
        for (int c = 0; c < 4; ++c) {
            const float L2i = __log2f(hiv[c] + 1e-8f);
            pv[c] = acc[r2][0][c] + b2v[c] * (acc[r2][2][c] + hiv[c] * acc[r2][1][c]
                                              - L2i * acc[r2][3][c]);
        }
        sRed4[g][row * 8 + dq] = make_float4(pv[0], pv[1], pv[2], pv[3]);
    }
    __syncthreads();

    // ---- Final reduce, two-level: 512 threads x 8, then 128 x 4 ----
    {
        const int q4 = t >> 7, rr = (t >> 5) & 3, dd = t & 31;
        const float* pR = (const float*)sRed4;
        float s = 0.f;
        #pragma unroll
        for (int g2 = 0; g2 < 8; ++g2)
            s += pR[(q4 * 8 + g2) * 132 + rr * 32 + dd];
        sFin[q4][rr][dd] = s;
    }
    __syncthreads();
    if (t < 128) {
        const int rr = t >> 5, dd = t & 31;
        const float sum = (sFin[0][rr][dd] + sFin[1][rr][dd])
                        + (sFin[2][rr][dd] + sFin[3][rr][dd]);
        const float hi  = h_b[(size_t)(i0 + rr) * ND + dd];
        const float L2i = __log2f(hi + 1e-8f);
        const float b2d = beta[dd] * LN2;
        out[(size_t)(b * NN + i0 + rr) * ND + dd] =
            sum + hi * (sS1[rr] - b2d * L2i * sS3[rr]);
    }
}

extern "C" void kernel_launch(void* const* d_in, const int* in_sizes, int n_in,
                              void* d_out, int out_size, void* d_ws, size_t ws_size,
                              hipStream_t stream) {
    // input order: t, h, pe, E, A, Wk, bk, Wq, bq, beta
    const float* h    = (const float*)d_in[1];
    const float* pe   = (const float*)d_in[2];
    const float* E    = (const float*)d_in[3];
    const float* A    = (const float*)d_in[4];
    const float* Wk   = (const float*)d_in[5];
    const float* bk   = (const float*)d_in[6];
    const float* Wq   = (const float*)d_in[7];
    const float* bq   = (const float*)d_in[8];
    const float* beta = (const float*)d_in[9];
    float* out = (float*)d_out;

    fpg_kernel<<<NB * NN / 4, 512, 0, stream>>>(h, pe, E, A, Wk, bk, Wq, bq, beta, out);
}

// Round 9
// 17.000 us; speedup vs baseline: 2.0337x; 2.0337x over previous
//
#include <hip/hip_runtime.h>
#include <math.h>

constexpr int NB = 4;
constexpr int NN = 512;
constexpr int ND = 32;
constexpr int NPE = 16;
constexpr float INV_SQRT_D = 0.17677669529663687f; // 1/sqrt(32)
constexpr float KSHARP = 10.0f;
constexpr float LN2 = 0.69314718055994531f;

// Single fused kernel. TI=4 rows/block, 512 threads, 512 blocks.
// out[i,d] = A2 + b2*(A4 + hi*A3 - L2i*A5) + hi*(S1 - b2*L2i*S3)
//   c2=W*e*sig, c3=W*(1-sig), c4=W*sig, e=Ej-Ei, b2=beta_d*ln2
//   A2=sum c2*hj, A3=sum c3*log2(hj+eps), A4=sum c4*hj*log2(hj+eps), A5=sum c4*hj
// NOTE (R8): do NOT add register prefetch arrays here — __launch_bounds__(512,4)
// caps VGPR at ~128; R7's pjv/hva/hvb arrays forced full scratch spill (60 MB
// writes, 2x slowdown). This exact version measured 17.01 us.
__global__ __launch_bounds__(512, 4) void fpg_kernel(
    const float* __restrict__ h,
    const float* __restrict__ pe,
    const float* __restrict__ E,
    const float* __restrict__ A,
    const float* __restrict__ Wk,
    const float* __restrict__ bk,
    const float* __restrict__ Wq,
    const float* __restrict__ bq,
    const float* __restrict__ beta,
    float* __restrict__ out)
{
    const int blk = blockIdx.x;          // 512 blocks = 4 batches x 128 tiles
    const int b   = blk >> 7;
    const int i0  = (blk & 127) << 2;    // 4 rows per block
    const int t   = threadIdx.x;

    __shared__ __align__(16) float sK[4][ND];
    __shared__ float sKWq[4][20];                       // 17 used
    __shared__ __align__(16) float sCoefP[3][2][NN][2]; // [coef][rowpair][j][rowinpair] 24 KB
    __shared__ float sPart[4][2][4];                    // [row][wave-half][max,s0,s1,s2]
    __shared__ float sS1[4], sS3[4];
    __shared__ __align__(16) float4 sRed4[32][33];      // [g][row*8+dq], stride 33 vs conflicts

    const float* h_b  = h  + (size_t)b * NN * ND;
    const float* pe_b = pe + (size_t)b * NN * NPE;

    // ---- Phase A: K rows = pe_i @ Wk + bk ----
    if (t < 128) {
        const int r = t >> 5, d = t & 31;
        const float* pe_i = pe_b + (size_t)(i0 + r) * NPE;
        float k = bk[d];
        #pragma unroll
        for (int p = 0; p < NPE; ++p) k = fmaf(pe_i[p], Wk[p * ND + d], k);
        sK[r][d] = k;
    }
    __syncthreads();

    // ---- Phase A2: KWq[r][p] = K_r . Wq[p,:]; [16] = K_r . bq ----
    if (t < 128) {
        const int r = t >> 5, q = t & 31;
        if (q < 17) {
            const float* wrow = (q < 16) ? (Wq + q * ND) : bq;
            float acc = 0.f;
            #pragma unroll
            for (int d = 0; d < ND; ++d) acc = fmaf(sK[r][d], wrow[d], acc);
            sKWq[r][q] = acc;
        }
    }
    __syncthreads();

    // ---- Phase B: row r = t>>7 (2 waves per row), 4 j per thread ----
    const int r    = t >> 7;
    const int jj   = t & 127;
    const int i    = i0 + r;
    const int lane = t & 63;
    const int wh   = (t >> 6) & 1;

    float kq[17];
    #pragma unroll
    for (int p = 0; p < 17; ++p) kq[p] = sKWq[r][p];
    const float Ei = E[i];
    const float* Arow = A + (size_t)i * NN;

    float sc[4], ed[4], sg[4];
    #pragma unroll
    for (int k = 0; k < 4; ++k) {
        const int j = jj + (k << 7);
        const float4* pj = (const float4*)(pe_b + (size_t)j * NPE);
        const float4 p0 = pj[0], p1 = pj[1], p2 = pj[2], p3 = pj[3];
        float dot = kq[16];
        dot = fmaf(p0.x, kq[0],  dot); dot = fmaf(p0.y, kq[1],  dot);
        dot = fmaf(p0.z, kq[2],  dot); dot = fmaf(p0.w, kq[3],  dot);
        dot = fmaf(p1.x, kq[4],  dot); dot = fmaf(p1.y, kq[5],  dot);
        dot = fmaf(p1.z, kq[6],  dot); dot = fmaf(p1.w, kq[7],  dot);
        dot = fmaf(p2.x, kq[8],  dot); dot = fmaf(p2.y, kq[9],  dot);
        dot = fmaf(p2.z, kq[10], dot); dot = fmaf(p2.w, kq[11], dot);
        dot = fmaf(p3.x, kq[12], dot); dot = fmaf(p3.y, kq[13], dot);
        dot = fmaf(p3.z, kq[14], dot); dot = fmaf(p3.w, kq[15], dot);
        sc[k] = Arow[j] * dot * INV_SQRT_D;
        const float e = E[j] - Ei;
        ed[k] = e;
        sg[k] = 1.0f / (1.0f + __expf(-KSHARP * e));
    }

    // ---- Phase C: per-row softmax stats over this row's 2 waves ----
    float m = fmaxf(fmaxf(sc[0], sc[1]), fmaxf(sc[2], sc[3]));
    #pragma unroll
    for (int off = 32; off >= 1; off >>= 1) m = fmaxf(m, __shfl_xor(m, off));
    if (lane == 0) sPart[r][wh][0] = m;
    __syncthreads();
    const float M = fmaxf(sPart[r][0][0], sPart[r][1][0]);

    float eh[4];
    float s0 = 0.f, s1 = 0.f, s2 = 0.f;
    #pragma unroll
    for (int k = 0; k < 4; ++k) {
        eh[k] = __expf(sc[k] - M);
        const float om = 1.0f - sg[k];
        s0 += eh[k];
        s1 += eh[k] * ed[k] * om;
        s2 += eh[k] * om;
    }
    #pragma unroll
    for (int off = 32; off >= 1; off >>= 1) {
        s0 += __shfl_xor(s0, off);
        s1 += __shfl_xor(s1, off);
        s2 += __shfl_xor(s2, off);
    }
    if (lane == 0) { sPart[r][wh][1] = s0; sPart[r][wh][2] = s1; sPart[r][wh][3] = s2; }
    __syncthreads();
    const float S   = sPart[r][0][1] + sPart[r][1][1];
    const float inv = 1.0f / S;
    if ((t & 127) == 0) {
        sS1[r] = (sPart[r][0][2] + sPart[r][1][2]) * inv;   // sum W*e*(1-sig)
        sS3[r] = (sPart[r][0][3] + sPart[r][1][3]) * inv;   // sum W*(1-sig)
    }

    // ---- Phase D: publish c2,c3,c4 — stride-8B writes, near-conflict-free ----
    const int rp = r >> 1, ri = r & 1;
    #pragma unroll
    for (int k = 0; k < 4; ++k) {
        const int j = jj + (k << 7);
        const float w  = eh[k] * inv;
        const float c4 = w * sg[k];
        const float c3 = w - c4;
        const float c2 = w * ed[k] * sg[k];
        sCoefP[0][rp][j][ri] = c2;
        sCoefP[1][rp][j][ri] = c3;
        sCoefP[2][rp][j][ri] = c4;
    }
    __syncthreads();

    // ---- Phase E: thread = (rh row-pair, dq d-quad, g j-group), 16 j each ----
    const int rh = t >> 8;             // 0: rows 0-1, 1: rows 2-3
    const int dq = t & 7;              // d-quad
    const int d0 = dq << 2;
    const int g  = (t >> 3) & 31;      // 32 j-groups

    float acc[2][4][4] = {};           // [row-in-pair][A2,A3,A4,A5][comp]
    #pragma unroll
    for (int q = 0; q < 16; ++q) {
        const int j = (q << 5) + g;
        const float2 C2 = *(const float2*)&sCoefP[0][rh][j][0];
        const float2 C3 = *(const float2*)&sCoefP[1][rh][j][0];
        const float2 C4 = *(const float2*)&sCoefP[2][rh][j][0];
        const float4 hv4 = *(const float4*)(h_b + (size_t)j * ND + d0);
        const float hvv[4] = {hv4.x, hv4.y, hv4.z, hv4.w};
        const float cc2[2] = {C2.x, C2.y};
        const float cc3[2] = {C3.x, C3.y};
        const float cc4[2] = {C4.x, C4.y};
        #pragma unroll
        for (int c = 0; c < 4; ++c) {
            const float hvc = hvv[c];
            const float l2  = __log2f(hvc + 1e-8f);
            const float hl  = hvc * l2;
            #pragma unroll
            for (int r2 = 0; r2 < 2; ++r2) {
                acc[r2][0][c] = fmaf(cc2[r2], hvc, acc[r2][0][c]);
                acc[r2][1][c] = fmaf(cc3[r2], l2,  acc[r2][1][c]);
                acc[r2][2][c] = fmaf(cc4[r2], hl,  acc[r2][2][c]);
                acc[r2][3][c] = fmaf(cc4[r2], hvc, acc[r2][3][c]);
            }
        }
    }
    const float4 bet = *(const float4*)(beta + d0);
    const float b2v[4] = {bet.x * LN2, bet.y * LN2, bet.z * LN2, bet.w * LN2};
    #pragma unroll
    for (int r2 = 0; r2 < 2; ++r2) {
        const int row = (rh << 1) + r2;
        const float4 hi4 = *(const float4*)(h_b + (size_t)(i0 + row) * ND + d0);
        const float hiv[4] = {hi4.x, hi4.y, hi4.z, hi4.w};
        float pv[4];
        #pragma unroll
        for (int c = 0; c < 4; ++c) {
            const float L2i = __log2f(hiv[c] + 1e-8f);
            pv[c] = acc[r2][0][c] + b2v[c] * (acc[r2][2][c] + hiv[c] * acc[r2][1][c]
                                              - L2i * acc[r2][3][c]);
        }
        sRed4[g][row * 8 + dq] = make_float4(pv[0], pv[1], pv[2], pv[3]);
    }
    __syncthreads();

    // ---- Final reduce + constant term + store (128 threads) ----
    if (t < 128) {
        const int rr = t >> 5, dd = t & 31;
        const float* pR = (const float*)sRed4;
        float sum = 0.f;
        #pragma unroll
        for (int g2 = 0; g2 < 32; ++g2) sum += pR[g2 * 132 + rr * 32 + dd];
        const float hi  = h_b[(size_t)(i0 + rr) * ND + dd];
        const float L2i = __log2f(hi + 1e-8f);
        const float b2d = beta[dd] * LN2;
        out[(size_t)(b * NN + i0 + rr) * ND + dd] =
            sum + hi * (sS1[rr] - b2d * L2i * sS3[rr]);
    }
}

extern "C" void kernel_launch(void* const* d_in, const int* in_sizes, int n_in,
                              void* d_out, int out_size, void* d_ws, size_t ws_size,
                              hipStream_t stream) {
    // input order: t, h, pe, E, A, Wk, bk, Wq, bq, beta
    const float* h    = (const float*)d_in[1];
    const float* pe   = (const float*)d_in[2];
    const float* E    = (const float*)d_in[3];
    const float* A    = (const float*)d_in[4];
    const float* Wk   = (const float*)d_in[5];
    const float* bk   = (const float*)d_in[6];
    const float* Wq   = (const float*)d_in[7];
    const float* bq   = (const float*)d_in[8];
    const float* beta = (const float*)d_in[9];
    float* out = (float*)d_out;

    fpg_kernel<<<NB * NN / 4, 512, 0, stream>>>(h, pe, E, A, Wk, bk, Wq, bq, beta, out);
}